// Round 1
// 442.329 us; speedup vs baseline: 1.0229x; 1.0229x over previous
//
#include <hip/hip_runtime.h>

#define BB 4
#define SS 1024
#define DD 1024
#define HH 16
#define DHH 64
#define MT (BB*SS)   // 4096 rows for QKV projection

typedef __bf16 bf16x8 __attribute__((ext_vector_type(8)));
typedef unsigned short u16x8 __attribute__((ext_vector_type(8)));
typedef unsigned short u16x4 __attribute__((ext_vector_type(4)));
typedef float f32x4 __attribute__((ext_vector_type(4)));

__device__ __forceinline__ bf16x8 as_bf16x8(u16x8 u) {
  union { u16x8 u; bf16x8 b; } c; c.u = u; return c.b;
}
__device__ __forceinline__ unsigned short f2bf(float f) {
  unsigned int u = __float_as_uint(f);
  return (unsigned short)((u + 0x7fffu + ((u >> 16) & 1u)) >> 16);
}
__device__ __forceinline__ float bf2f(unsigned short u) {
  return __uint_as_float((unsigned int)u << 16);
}

#define MFMA(a, b, c) __builtin_amdgcn_mfma_f32_16x16x32_bf16((a), (b), (c), 0, 0, 0)

typedef const __attribute__((address_space(1))) unsigned int* gas1;
typedef __attribute__((address_space(3))) unsigned int* las3;
__device__ __forceinline__ void gl_lds16(const void* g, void* l) {
  __builtin_amdgcn_global_load_lds((gas1)g, (las3)l, 16, 0, 0);
}

// ---------------------------------------------------------------------------
// conv_x3: fp32 -> bf16 for query/key/value in one dispatch (z picks input).
// ---------------------------------------------------------------------------
__global__ __launch_bounds__(256) void conv_x3(
    const float* __restrict__ q, const float* __restrict__ k,
    const float* __restrict__ v, unsigned short* __restrict__ out)
{
  const int zz = blockIdx.y;
  const float* in = (zz == 0) ? q : (zz == 1) ? k : v;
  unsigned short* o = out + (size_t)zz * MT * DD;
  const int i = (blockIdx.x * 256 + threadIdx.x) * 8;
  float4 x0 = *(const float4*)(in + i);
  float4 x1 = *(const float4*)(in + i + 4);
  u16x8 r;
  r[0]=f2bf(x0.x); r[1]=f2bf(x0.y); r[2]=f2bf(x0.z); r[3]=f2bf(x0.w);
  r[4]=f2bf(x1.x); r[5]=f2bf(x1.y); r[6]=f2bf(x1.z); r[7]=f2bf(x1.w);
  *(u16x8*)(o + i) = r;
}

// ---------------------------------------------------------------------------
// conv_wT3: W (K x N fp32) -> Wt (N x K bf16) for Wq/Wk/Wv in one dispatch.
// ---------------------------------------------------------------------------
__global__ __launch_bounds__(256) void conv_wT3(
    const float* __restrict__ wq, const float* __restrict__ wk,
    const float* __restrict__ wv, unsigned short* __restrict__ out)
{
  __shared__ unsigned short Ts[64][72];
  const int zz = blockIdx.z;
  const float* W = (zz == 0) ? wq : (zz == 1) ? wk : wv;
  unsigned short* Wt = out + (size_t)zz * DD * DD;
  const int tid = threadIdx.x;
  const int n0 = blockIdx.x * 64, k0 = blockIdx.y * 64;
  const int r = tid >> 2, cs = (tid & 3) * 16;
  const float* wp = W + (size_t)(k0 + r) * DD + n0 + cs;
  #pragma unroll
  for (int c = 0; c < 4; c++) {
    float4 x = *(const float4*)(wp + c*4);
    Ts[r][cs + c*4 + 0] = f2bf(x.x); Ts[r][cs + c*4 + 1] = f2bf(x.y);
    Ts[r][cs + c*4 + 2] = f2bf(x.z); Ts[r][cs + c*4 + 3] = f2bf(x.w);
  }
  __syncthreads();
  const int nl = tid >> 2, ks = (tid & 3) * 16;
  u16x8 o0, o1;
  #pragma unroll
  for (int e = 0; e < 8; e++) { o0[e] = Ts[ks + e][nl]; o1[e] = Ts[ks + 8 + e][nl]; }
  unsigned short* op = Wt + (size_t)(n0 + nl) * DD + k0 + ks;
  *(u16x8*)op = o0;
  *(u16x8*)(op + 8) = o1;
}

// ---------------------------------------------------------------------------
// gemm3: all three projections in ONE dispatch (grid.z = 3 -> 768 blocks).
// m97-proven structure: BM=128, BN=128, BK=64, 4 waves (2x2), wave tile
// 64x64, acc 4x4, 32 MFMA per K-step per wave, global_load_lds width=16.
// z=0 -> Qb row-major, z=1 -> Kb row-major, z=2 -> Vt transposed.
// ---------------------------------------------------------------------------
__global__ __launch_bounds__(256) void gemm3(
    const unsigned short* __restrict__ X3, const unsigned short* __restrict__ Wt3,
    const float* __restrict__ bq, const float* __restrict__ bk,
    const float* __restrict__ bv, unsigned short* __restrict__ Qb,
    unsigned short* __restrict__ Kb, unsigned short* __restrict__ Vt)
{
  __shared__ union {
    struct { unsigned short A[128 * 64]; unsigned short B[128 * 64]; } s;
    unsigned short T[128][136];   // 16B-aligned rows (272 B stride)
  } sm;

  const int zz = blockIdx.z;
  const unsigned short* A  = X3  + (size_t)zz * MT * DD;
  const unsigned short* Bt = Wt3 + (size_t)zz * DD * DD;
  const float* bias = (zz == 0) ? bq : (zz == 1) ? bk : bv;

  const int tid  = threadIdx.x;
  const int lane = tid & 63, wave = tid >> 6;
  const int quad = lane >> 4, l16 = lane & 15;
  const int wm = (wave >> 1) * 64, wn = (wave & 1) * 64;
  const int m0 = blockIdx.x * 128, n0 = blockIdx.y * 128;
  const int lrow = lane >> 3, lcol = (lane & 7) * 8;

  f32x4 acc[4][4] = {};

  for (int k0 = 0; k0 < DD; k0 += 64) {
    #pragma unroll
    for (int r = 0; r < 4; r++) {
      const int c = wave * 4 + r;        // 16 chunks x 1 KB, each 8 rows
      gl_lds16(A  + (size_t)(m0 + c*8 + lrow) * DD + k0 + lcol, &sm.s.A[c * 512]);
      gl_lds16(Bt + (size_t)(n0 + c*8 + lrow) * DD + k0 + lcol, &sm.s.B[c * 512]);
    }
    __syncthreads();

    #pragma unroll
    for (int ks = 0; ks < 2; ks++) {
      bf16x8 af[4], bfr[4];
      #pragma unroll
      for (int i = 0; i < 4; i++)
        af[i] = as_bf16x8(*(const u16x8*)&sm.s.A[(wm + i*16 + l16)*64 + ks*32 + quad*8]);
      #pragma unroll
      for (int j = 0; j < 4; j++)
        bfr[j] = as_bf16x8(*(const u16x8*)&sm.s.B[(wn + j*16 + l16)*64 + ks*32 + quad*8]);
      __builtin_amdgcn_s_setprio(1);
      #pragma unroll
      for (int i = 0; i < 4; i++)
        #pragma unroll
        for (int j = 0; j < 4; j++)
          acc[i][j] = MFMA(af[i], bfr[j], acc[i][j]);
      __builtin_amdgcn_s_setprio(0);
    }
    __syncthreads();
  }

  if (zz == 2) {
    #pragma unroll
    for (int j = 0; j < 4; j++) {
      const int nn = wn + j*16 + l16;
      const float bsv = bias[n0 + nn];
      #pragma unroll
      for (int i = 0; i < 4; i++)
        #pragma unroll
        for (int r = 0; r < 4; r++)
          sm.T[nn][wm + i*16 + quad*4 + r] = f2bf(acc[i][j][r] + bsv);
    }
    __syncthreads();
    const int nl = tid >> 1, ms = (tid & 1) * 64;
    unsigned short* op = Vt + (size_t)(n0 + nl) * MT + m0 + ms;
    #pragma unroll
    for (int e = 0; e < 8; e++)
      *(u16x8*)(op + e*8) = *(const u16x8*)&sm.T[nl][ms + e*8];
  } else {
    unsigned short* Out = (zz == 0) ? Qb : Kb;
    #pragma unroll
    for (int j = 0; j < 4; j++) {
      const int col = n0 + wn + j*16 + l16;
      const float bsv = bias[col];
      #pragma unroll
      for (int i = 0; i < 4; i++)
        #pragma unroll
        for (int r = 0; r < 4; r++) {
          const int row = m0 + wm + i*16 + quad*4 + r;
          Out[(size_t)row * DD + col] = f2bf(acc[i][j][r] + bsv);
        }
    }
  }
}

// ---------------------------------------------------------------------------
// fused QK^T -> softmax -> P(bf16) in LDS -> (attn store fused into P@V).
// Block = 4 waves, owns 32 q-rows of one (b,h); wave w holds score cols
// [w*256, w*256+256) in 128 VGPRs of accumulators.
// attn/ctx stores are NONTEMPORAL (write-only data; keep K/V L2-resident).
// ---------------------------------------------------------------------------
__global__ __launch_bounds__(256, 2) void fused_attn(
    const unsigned short* __restrict__ Qb, const unsigned short* __restrict__ Kb,
    const unsigned short* __restrict__ Vt, float* __restrict__ attn,
    float* __restrict__ ctx)
{
  __shared__ unsigned short Ps[32][1032];
  __shared__ float redm[4][32];
  __shared__ float redl[4][32];

  const int tid  = threadIdx.x;
  const int lane = tid & 63, w = tid >> 6;
  const int quad = lane >> 4, l16 = lane & 15;
  const int q0 = blockIdx.x * 32;
  const int z  = blockIdx.y;             // z = h*B + b
  const int b = z & 3, h = z >> 2;
  const int cbase = w * 256;

  const unsigned short* qbase = Qb + (size_t)b * SS * DD + h * DHH;
  const unsigned short* kbase = Kb + (size_t)b * SS * DD + h * DHH;

  bf16x8 aq[2][2];
  #pragma unroll
  for (int i = 0; i < 2; i++)
    #pragma unroll
    for (int kk = 0; kk < 2; kk++)
      aq[i][kk] = as_bf16x8(*(const u16x8*)(
          qbase + (size_t)(q0 + i*16 + l16) * DD + kk*32 + quad*8));

  // ---- Phase 1: S = Q K^T ----
  f32x4 acc[2][16] = {};
  #pragma unroll
  for (int t = 0; t < 16; t++) {
    const unsigned short* kp = kbase + (size_t)(cbase + t*16 + l16) * DD + quad*8;
    bf16x8 b0 = as_bf16x8(*(const u16x8*)kp);
    bf16x8 b1 = as_bf16x8(*(const u16x8*)(kp + 32));
    __builtin_amdgcn_s_setprio(1);
    acc[0][t] = MFMA(aq[0][0], b0, acc[0][t]);
    acc[0][t] = MFMA(aq[0][1], b1, acc[0][t]);
    acc[1][t] = MFMA(aq[1][0], b0, acc[1][t]);
    acc[1][t] = MFMA(aq[1][1], b1, acc[1][t]);
    __builtin_amdgcn_s_setprio(0);
  }

  // ---- Phase 2: softmax ----
  float pm[2][4];
  #pragma unroll
  for (int i = 0; i < 2; i++)
    #pragma unroll
    for (int rr = 0; rr < 4; rr++) pm[i][rr] = -3.4e38f;
  #pragma unroll
  for (int i = 0; i < 2; i++)
    #pragma unroll
    for (int t = 0; t < 16; t++)
      #pragma unroll
      for (int rr = 0; rr < 4; rr++) pm[i][rr] = fmaxf(pm[i][rr], acc[i][t][rr]);
  #pragma unroll
  for (int off = 1; off < 16; off <<= 1)
    #pragma unroll
    for (int i = 0; i < 2; i++)
      #pragma unroll
      for (int rr = 0; rr < 4; rr++)
        pm[i][rr] = fmaxf(pm[i][rr], __shfl_xor(pm[i][rr], off));
  if (l16 == 0) {
    #pragma unroll
    for (int i = 0; i < 2; i++)
      #pragma unroll
      for (int rr = 0; rr < 4; rr++)
        redm[w][i*16 + quad*4 + rr] = pm[i][rr];
  }
  __syncthreads();
  float cc[2][4];
  #pragma unroll
  for (int i = 0; i < 2; i++)
    #pragma unroll
    for (int rr = 0; rr < 4; rr++) {
      const int r = i*16 + quad*4 + rr;
      float m = fmaxf(fmaxf(redm[0][r], redm[1][r]), fmaxf(redm[2][r], redm[3][r]));
      cc[i][rr] = m * 0.125f;
    }

  float ps[2][4] = {};
  #pragma unroll
  for (int i = 0; i < 2; i++)
    #pragma unroll
    for (int t = 0; t < 16; t++)
      #pragma unroll
      for (int rr = 0; rr < 4; rr++) {
        float e = __expf(fmaf(acc[i][t][rr], 0.125f, -cc[i][rr]));
        acc[i][t][rr] = e;
        ps[i][rr] += e;
      }
  #pragma unroll
  for (int off = 1; off < 16; off <<= 1)
    #pragma unroll
    for (int i = 0; i < 2; i++)
      #pragma unroll
      for (int rr = 0; rr < 4; rr++)
        ps[i][rr] += __shfl_xor(ps[i][rr], off);
  if (l16 == 0) {
    #pragma unroll
    for (int i = 0; i < 2; i++)
      #pragma unroll
      for (int rr = 0; rr < 4; rr++)
        redl[w][i*16 + quad*4 + rr] = ps[i][rr];
  }
  __syncthreads();
  float inv[2][4];
  #pragma unroll
  for (int i = 0; i < 2; i++)
    #pragma unroll
    for (int rr = 0; rr < 4; rr++) {
      const int r = i*16 + quad*4 + rr;
      inv[i][rr] = 1.0f / (redl[0][r] + redl[1][r] + redl[2][r] + redl[3][r]);
    }

  // ---- Phase 3: normalized P (bf16) into LDS ----
  #pragma unroll
  for (int i = 0; i < 2; i++)
    #pragma unroll
    for (int t = 0; t < 16; t++) {
      const int col = cbase + t*16 + l16;
      #pragma unroll
      for (int rr = 0; rr < 4; rr++)
        Ps[i*16 + quad*4 + rr][col] = f2bf(acc[i][t][rr] * inv[i][rr]);
    }
  __syncthreads();

  // ---- Phase 4+5 fused: ctx = P @ V, with one attn row streamed out
  // (nontemporal) per PV iteration so stores drain under MFMA.
  float* slab = attn + ((size_t)z * SS + q0) * SS;
  const unsigned short* vbase = Vt + (size_t)(h*DHH + w*16 + l16) * MT + b*SS + quad*8;
  f32x4 accp[2] = {};
  #pragma unroll 4
  for (int ks = 0; ks < 32; ks++) {
    bf16x8 bv = as_bf16x8(*(const u16x8*)(vbase + ks*32));
    bf16x8 a0 = as_bf16x8(*(const u16x8*)&Ps[l16][ks*32 + quad*8]);
    bf16x8 a1 = as_bf16x8(*(const u16x8*)&Ps[16 + l16][ks*32 + quad*8]);
    __builtin_amdgcn_s_setprio(1);
    accp[0] = MFMA(a0, bv, accp[0]);
    accp[1] = MFMA(a1, bv, accp[1]);
    __builtin_amdgcn_s_setprio(0);
    // attn row ks of this block's 32x1024 slab, fully coalesced float4
    u16x4 pv = *(const u16x4*)&Ps[ks][tid*4];
    f32x4 o;
    o[0] = bf2f(pv[0]); o[1] = bf2f(pv[1]); o[2] = bf2f(pv[2]); o[3] = bf2f(pv[3]);
    __builtin_nontemporal_store(o, (f32x4*)(slab + (size_t)ks * SS + tid*4));
  }
  #pragma unroll
  for (int i = 0; i < 2; i++)
    #pragma unroll
    for (int rr = 0; rr < 4; rr++)
      __builtin_nontemporal_store(
          accp[i][rr],
          &ctx[(size_t)(b*SS + q0 + i*16 + quad*4 + rr) * DD + h*DHH + w*16 + l16]);
}

extern "C" void kernel_launch(void* const* d_in, const int* in_sizes, int n_in,
                              void* d_out, int out_size, void* d_ws, size_t ws_size,
                              hipStream_t stream) {
  const float* query = (const float*)d_in[0];
  const float* key   = (const float*)d_in[1];
  const float* value = (const float*)d_in[2];
  const float* Wq    = (const float*)d_in[3];
  const float* bq    = (const float*)d_in[4];
  const float* Wk    = (const float*)d_in[5];
  const float* bk    = (const float*)d_in[6];
  const float* Wv    = (const float*)d_in[7];
  const float* bv    = (const float*)d_in[8];

  float* ctx  = (float*)d_out;
  float* attn = ctx + (size_t)BB * SS * DD;

  // Persistent bf16 Q/K/Vt in ws (24 MB, known-safe size)
  unsigned short* Qb = (unsigned short*)d_ws;
  unsigned short* Kb = Qb + (size_t)MT * DD;
  unsigned short* Vt = Kb + (size_t)MT * DD;

  // Transient staging (X3: 24 MB, Wt3: 6 MB) lives in the attn region of
  // d_out — dead by the time fused_attn overwrites it.
  unsigned short* X3  = (unsigned short*)attn;
  unsigned short* Wt3 = X3 + (size_t)3 * MT * DD;

  dim3 gc(MT * DD / (256 * 8), 3);                   // 2048 x 3
  conv_x3<<<gc, 256, 0, stream>>>(query, key, value, X3);

  dim3 gw(DD / 64, DD / 64, 3);                      // 16 x 16 x 3
  conv_wT3<<<gw, 256, 0, stream>>>(Wq, Wk, Wv, Wt3);

  dim3 gg(MT / 128, DD / 128, 3);                    // 32 x 8 x 3 = 768 blocks
  gemm3<<<gg, 256, 0, stream>>>(X3, Wt3, bq, bk, bv, Qb, Kb, Vt);

  dim3 g2(SS / 32, BB * HH);                         // 32 x 64
  fused_attn<<<g2, 256, 0, stream>>>(Qb, Kb, Vt, attn, ctx);
}

// Round 2
// 439.262 us; speedup vs baseline: 1.0300x; 1.0070x over previous
//
#include <hip/hip_runtime.h>

#define BB 4
#define SS 1024
#define DD 1024
#define HH 16
#define DHH 64
#define MT (BB*SS)   // 4096 rows for QKV projection

typedef __bf16 bf16x8 __attribute__((ext_vector_type(8)));
typedef unsigned short u16x8 __attribute__((ext_vector_type(8)));
typedef unsigned short u16x4 __attribute__((ext_vector_type(4)));
typedef float f32x4 __attribute__((ext_vector_type(4)));

__device__ __forceinline__ bf16x8 as_bf16x8(u16x8 u) {
  union { u16x8 u; bf16x8 b; } c; c.u = u; return c.b;
}
__device__ __forceinline__ unsigned short f2bf(float f) {
  unsigned int u = __float_as_uint(f);
  return (unsigned short)((u + 0x7fffu + ((u >> 16) & 1u)) >> 16);
}
__device__ __forceinline__ float bf2f(unsigned short u) {
  return __uint_as_float((unsigned int)u << 16);
}

#define MFMA(a, b, c) __builtin_amdgcn_mfma_f32_16x16x32_bf16((a), (b), (c), 0, 0, 0)

typedef const __attribute__((address_space(1))) unsigned int* gas1;
typedef __attribute__((address_space(3))) unsigned int* las3;
__device__ __forceinline__ void gl_lds16(const void* g, void* l) {
  __builtin_amdgcn_global_load_lds((gas1)g, (las3)l, 16, 0, 0);
}

// ---------------------------------------------------------------------------
// conv_x3: fp32 -> bf16 for query/key/value in one dispatch (z picks input).
// ---------------------------------------------------------------------------
__global__ __launch_bounds__(256) void conv_x3(
    const float* __restrict__ q, const float* __restrict__ k,
    const float* __restrict__ v, unsigned short* __restrict__ out)
{
  const int zz = blockIdx.y;
  const float* in = (zz == 0) ? q : (zz == 1) ? k : v;
  unsigned short* o = out + (size_t)zz * MT * DD;
  const int i = (blockIdx.x * 256 + threadIdx.x) * 8;
  float4 x0 = *(const float4*)(in + i);
  float4 x1 = *(const float4*)(in + i + 4);
  u16x8 r;
  r[0]=f2bf(x0.x); r[1]=f2bf(x0.y); r[2]=f2bf(x0.z); r[3]=f2bf(x0.w);
  r[4]=f2bf(x1.x); r[5]=f2bf(x1.y); r[6]=f2bf(x1.z); r[7]=f2bf(x1.w);
  *(u16x8*)(o + i) = r;
}

// ---------------------------------------------------------------------------
// conv_wT3: W (K x N fp32) -> Wt (N x K bf16) for Wq/Wk/Wv in one dispatch.
// ---------------------------------------------------------------------------
__global__ __launch_bounds__(256) void conv_wT3(
    const float* __restrict__ wq, const float* __restrict__ wk,
    const float* __restrict__ wv, unsigned short* __restrict__ out)
{
  __shared__ unsigned short Ts[64][72];
  const int zz = blockIdx.z;
  const float* W = (zz == 0) ? wq : (zz == 1) ? wk : wv;
  unsigned short* Wt = out + (size_t)zz * DD * DD;
  const int tid = threadIdx.x;
  const int n0 = blockIdx.x * 64, k0 = blockIdx.y * 64;
  const int r = tid >> 2, cs = (tid & 3) * 16;
  const float* wp = W + (size_t)(k0 + r) * DD + n0 + cs;
  #pragma unroll
  for (int c = 0; c < 4; c++) {
    float4 x = *(const float4*)(wp + c*4);
    Ts[r][cs + c*4 + 0] = f2bf(x.x); Ts[r][cs + c*4 + 1] = f2bf(x.y);
    Ts[r][cs + c*4 + 2] = f2bf(x.z); Ts[r][cs + c*4 + 3] = f2bf(x.w);
  }
  __syncthreads();
  const int nl = tid >> 2, ks = (tid & 3) * 16;
  u16x8 o0, o1;
  #pragma unroll
  for (int e = 0; e < 8; e++) { o0[e] = Ts[ks + e][nl]; o1[e] = Ts[ks + 8 + e][nl]; }
  unsigned short* op = Wt + (size_t)(n0 + nl) * DD + k0 + ks;
  *(u16x8*)op = o0;
  *(u16x8*)(op + 8) = o1;
}

// ---------------------------------------------------------------------------
// gemm3: all three projections in ONE dispatch (grid.z = 3 -> 768 blocks).
// m97-proven structure: BM=128, BN=128, BK=64, 4 waves (2x2), wave tile
// 64x64, acc 4x4, 32 MFMA per K-step per wave, global_load_lds width=16.
// z=0 -> Qb row-major, z=1 -> Kb row-major, z=2 -> Vt transposed.
// Grid mapping note: same-m0 blocks are 32 apart in flat id -> same XCD
// (32 % 8 == 0), so the A panel is fetched once per m0; B amplification
// (8 XCDs x 2 MB/z) is the min for M >> N. No swizzle needed here.
// ---------------------------------------------------------------------------
__global__ __launch_bounds__(256) void gemm3(
    const unsigned short* __restrict__ X3, const unsigned short* __restrict__ Wt3,
    const float* __restrict__ bq, const float* __restrict__ bk,
    const float* __restrict__ bv, unsigned short* __restrict__ Qb,
    unsigned short* __restrict__ Kb, unsigned short* __restrict__ Vt)
{
  __shared__ union {
    struct { unsigned short A[128 * 64]; unsigned short B[128 * 64]; } s;
    unsigned short T[128][136];   // 16B-aligned rows (272 B stride)
  } sm;

  const int zz = blockIdx.z;
  const unsigned short* A  = X3  + (size_t)zz * MT * DD;
  const unsigned short* Bt = Wt3 + (size_t)zz * DD * DD;
  const float* bias = (zz == 0) ? bq : (zz == 1) ? bk : bv;

  const int tid  = threadIdx.x;
  const int lane = tid & 63, wave = tid >> 6;
  const int quad = lane >> 4, l16 = lane & 15;
  const int wm = (wave >> 1) * 64, wn = (wave & 1) * 64;
  const int m0 = blockIdx.x * 128, n0 = blockIdx.y * 128;
  const int lrow = lane >> 3, lcol = (lane & 7) * 8;

  f32x4 acc[4][4] = {};

  for (int k0 = 0; k0 < DD; k0 += 64) {
    #pragma unroll
    for (int r = 0; r < 4; r++) {
      const int c = wave * 4 + r;        // 16 chunks x 1 KB, each 8 rows
      gl_lds16(A  + (size_t)(m0 + c*8 + lrow) * DD + k0 + lcol, &sm.s.A[c * 512]);
      gl_lds16(Bt + (size_t)(n0 + c*8 + lrow) * DD + k0 + lcol, &sm.s.B[c * 512]);
    }
    __syncthreads();

    #pragma unroll
    for (int ks = 0; ks < 2; ks++) {
      bf16x8 af[4], bfr[4];
      #pragma unroll
      for (int i = 0; i < 4; i++)
        af[i] = as_bf16x8(*(const u16x8*)&sm.s.A[(wm + i*16 + l16)*64 + ks*32 + quad*8]);
      #pragma unroll
      for (int j = 0; j < 4; j++)
        bfr[j] = as_bf16x8(*(const u16x8*)&sm.s.B[(wn + j*16 + l16)*64 + ks*32 + quad*8]);
      __builtin_amdgcn_s_setprio(1);
      #pragma unroll
      for (int i = 0; i < 4; i++)
        #pragma unroll
        for (int j = 0; j < 4; j++)
          acc[i][j] = MFMA(af[i], bfr[j], acc[i][j]);
      __builtin_amdgcn_s_setprio(0);
    }
    __syncthreads();
  }

  if (zz == 2) {
    #pragma unroll
    for (int j = 0; j < 4; j++) {
      const int nn = wn + j*16 + l16;
      const float bsv = bias[n0 + nn];
      #pragma unroll
      for (int i = 0; i < 4; i++)
        #pragma unroll
        for (int r = 0; r < 4; r++)
          sm.T[nn][wm + i*16 + quad*4 + r] = f2bf(acc[i][j][r] + bsv);
    }
    __syncthreads();
    const int nl = tid >> 1, ms = (tid & 1) * 64;
    unsigned short* op = Vt + (size_t)(n0 + nl) * MT + m0 + ms;
    #pragma unroll
    for (int e = 0; e < 8; e++)
      *(u16x8*)(op + e*8) = *(const u16x8*)&sm.T[nl][ms + e*8];
  } else {
    unsigned short* Out = (zz == 0) ? Qb : Kb;
    #pragma unroll
    for (int j = 0; j < 4; j++) {
      const int col = n0 + wn + j*16 + l16;
      const float bsv = bias[col];
      #pragma unroll
      for (int i = 0; i < 4; i++)
        #pragma unroll
        for (int r = 0; r < 4; r++) {
          const int row = m0 + wm + i*16 + quad*4 + r;
          Out[(size_t)row * DD + col] = f2bf(acc[i][j][r] + bsv);
        }
    }
  }
}

// ---------------------------------------------------------------------------
// fused QK^T -> softmax -> P(bf16) in LDS -> (attn store fused into P@V).
// Block = 4 waves, owns 32 q-rows of one (b,h); wave w holds score cols
// [w*256, w*256+256) in 128 VGPRs of accumulators.
// attn/ctx stores are NONTEMPORAL (write-only data; keep K/V L2-resident).
// XCD-aware 1D grid: 2048 = 8 XCDs x 8 z x 32 q-blocks. All 32 q-blocks
// sharing one (b,h)'s K/V panels land on ONE XCD -> panels fetched from
// HBM once per z instead of 8x (saves ~100 MB fetch).
// ---------------------------------------------------------------------------
__global__ __launch_bounds__(256, 2) void fused_attn(
    const unsigned short* __restrict__ Qb, const unsigned short* __restrict__ Kb,
    const unsigned short* __restrict__ Vt, float* __restrict__ attn,
    float* __restrict__ ctx)
{
  __shared__ unsigned short Ps[32][1032];
  __shared__ float redm[4][32];
  __shared__ float redl[4][32];

  const int tid  = threadIdx.x;
  const int lane = tid & 63, w = tid >> 6;
  const int quad = lane >> 4, l16 = lane & 15;

  // XCD-aware bijective swizzle (assumes XCD = flat_bid % 8 round-robin;
  // perf heuristic only, correctness independent of mapping).
  const int bid   = blockIdx.x;          // 0..2047
  const int xcd   = bid & 7;
  const int local = bid >> 3;            // 0..255 within this XCD
  const int z     = xcd * 8 + (local >> 5);   // 8 z-groups per XCD
  const int q0    = (local & 31) * 32;

  const int b = z & 3, h = z >> 2;
  const int cbase = w * 256;

  const unsigned short* qbase = Qb + (size_t)b * SS * DD + h * DHH;
  const unsigned short* kbase = Kb + (size_t)b * SS * DD + h * DHH;

  bf16x8 aq[2][2];
  #pragma unroll
  for (int i = 0; i < 2; i++)
    #pragma unroll
    for (int kk = 0; kk < 2; kk++)
      aq[i][kk] = as_bf16x8(*(const u16x8*)(
          qbase + (size_t)(q0 + i*16 + l16) * DD + kk*32 + quad*8));

  // ---- Phase 1: S = Q K^T ----
  f32x4 acc[2][16] = {};
  #pragma unroll
  for (int t = 0; t < 16; t++) {
    const unsigned short* kp = kbase + (size_t)(cbase + t*16 + l16) * DD + quad*8;
    bf16x8 b0 = as_bf16x8(*(const u16x8*)kp);
    bf16x8 b1 = as_bf16x8(*(const u16x8*)(kp + 32));
    __builtin_amdgcn_s_setprio(1);
    acc[0][t] = MFMA(aq[0][0], b0, acc[0][t]);
    acc[0][t] = MFMA(aq[0][1], b1, acc[0][t]);
    acc[1][t] = MFMA(aq[1][0], b0, acc[1][t]);
    acc[1][t] = MFMA(aq[1][1], b1, acc[1][t]);
    __builtin_amdgcn_s_setprio(0);
  }

  // ---- Phase 2: softmax ----
  float pm[2][4];
  #pragma unroll
  for (int i = 0; i < 2; i++)
    #pragma unroll
    for (int rr = 0; rr < 4; rr++) pm[i][rr] = -3.4e38f;
  #pragma unroll
  for (int i = 0; i < 2; i++)
    #pragma unroll
    for (int t = 0; t < 16; t++)
      #pragma unroll
      for (int rr = 0; rr < 4; rr++) pm[i][rr] = fmaxf(pm[i][rr], acc[i][t][rr]);
  #pragma unroll
  for (int off = 1; off < 16; off <<= 1)
    #pragma unroll
    for (int i = 0; i < 2; i++)
      #pragma unroll
      for (int rr = 0; rr < 4; rr++)
        pm[i][rr] = fmaxf(pm[i][rr], __shfl_xor(pm[i][rr], off));
  if (l16 == 0) {
    #pragma unroll
    for (int i = 0; i < 2; i++)
      #pragma unroll
      for (int rr = 0; rr < 4; rr++)
        redm[w][i*16 + quad*4 + rr] = pm[i][rr];
  }
  __syncthreads();
  float cc[2][4];
  #pragma unroll
  for (int i = 0; i < 2; i++)
    #pragma unroll
    for (int rr = 0; rr < 4; rr++) {
      const int r = i*16 + quad*4 + rr;
      float m = fmaxf(fmaxf(redm[0][r], redm[1][r]), fmaxf(redm[2][r], redm[3][r]));
      cc[i][rr] = m * 0.125f;
    }

  float ps[2][4] = {};
  #pragma unroll
  for (int i = 0; i < 2; i++)
    #pragma unroll
    for (int t = 0; t < 16; t++)
      #pragma unroll
      for (int rr = 0; rr < 4; rr++) {
        float e = __expf(fmaf(acc[i][t][rr], 0.125f, -cc[i][rr]));
        acc[i][t][rr] = e;
        ps[i][rr] += e;
      }
  #pragma unroll
  for (int off = 1; off < 16; off <<= 1)
    #pragma unroll
    for (int i = 0; i < 2; i++)
      #pragma unroll
      for (int rr = 0; rr < 4; rr++)
        ps[i][rr] += __shfl_xor(ps[i][rr], off);
  if (l16 == 0) {
    #pragma unroll
    for (int i = 0; i < 2; i++)
      #pragma unroll
      for (int rr = 0; rr < 4; rr++)
        redl[w][i*16 + quad*4 + rr] = ps[i][rr];
  }
  __syncthreads();
  float inv[2][4];
  #pragma unroll
  for (int i = 0; i < 2; i++)
    #pragma unroll
    for (int rr = 0; rr < 4; rr++) {
      const int r = i*16 + quad*4 + rr;
      inv[i][rr] = 1.0f / (redl[0][r] + redl[1][r] + redl[2][r] + redl[3][r]);
    }

  // ---- Phase 3: normalized P (bf16) into LDS ----
  #pragma unroll
  for (int i = 0; i < 2; i++)
    #pragma unroll
    for (int t = 0; t < 16; t++) {
      const int col = cbase + t*16 + l16;
      #pragma unroll
      for (int rr = 0; rr < 4; rr++)
        Ps[i*16 + quad*4 + rr][col] = f2bf(acc[i][t][rr] * inv[i][rr]);
    }
  __syncthreads();

  // ---- Phase 4+5 fused: ctx = P @ V, with one attn row streamed out
  // (nontemporal) per PV iteration so stores drain under MFMA.
  float* slab = attn + ((size_t)z * SS + q0) * SS;
  const unsigned short* vbase = Vt + (size_t)(h*DHH + w*16 + l16) * MT + b*SS + quad*8;
  f32x4 accp[2] = {};
  #pragma unroll 4
  for (int ks = 0; ks < 32; ks++) {
    bf16x8 bv = as_bf16x8(*(const u16x8*)(vbase + ks*32));
    bf16x8 a0 = as_bf16x8(*(const u16x8*)&Ps[l16][ks*32 + quad*8]);
    bf16x8 a1 = as_bf16x8(*(const u16x8*)&Ps[16 + l16][ks*32 + quad*8]);
    __builtin_amdgcn_s_setprio(1);
    accp[0] = MFMA(a0, bv, accp[0]);
    accp[1] = MFMA(a1, bv, accp[1]);
    __builtin_amdgcn_s_setprio(0);
    // attn row ks of this block's 32x1024 slab, fully coalesced float4
    u16x4 pv = *(const u16x4*)&Ps[ks][tid*4];
    f32x4 o;
    o[0] = bf2f(pv[0]); o[1] = bf2f(pv[1]); o[2] = bf2f(pv[2]); o[3] = bf2f(pv[3]);
    __builtin_nontemporal_store(o, (f32x4*)(slab + (size_t)ks * SS + tid*4));
  }
  #pragma unroll
  for (int i = 0; i < 2; i++)
    #pragma unroll
    for (int rr = 0; rr < 4; rr++)
      __builtin_nontemporal_store(
          accp[i][rr],
          &ctx[(size_t)(b*SS + q0 + i*16 + quad*4 + rr) * DD + h*DHH + w*16 + l16]);
}

extern "C" void kernel_launch(void* const* d_in, const int* in_sizes, int n_in,
                              void* d_out, int out_size, void* d_ws, size_t ws_size,
                              hipStream_t stream) {
  const float* query = (const float*)d_in[0];
  const float* key   = (const float*)d_in[1];
  const float* value = (const float*)d_in[2];
  const float* Wq    = (const float*)d_in[3];
  const float* bq    = (const float*)d_in[4];
  const float* Wk    = (const float*)d_in[5];
  const float* bk    = (const float*)d_in[6];
  const float* Wv    = (const float*)d_in[7];
  const float* bv    = (const float*)d_in[8];

  float* ctx  = (float*)d_out;
  float* attn = ctx + (size_t)BB * SS * DD;

  // Persistent bf16 Q/K/Vt in ws (24 MB, known-safe size)
  unsigned short* Qb = (unsigned short*)d_ws;
  unsigned short* Kb = Qb + (size_t)MT * DD;
  unsigned short* Vt = Kb + (size_t)MT * DD;

  // Transient staging (X3: 24 MB, Wt3: 6 MB) lives in the attn region of
  // d_out — dead by the time fused_attn overwrites it.
  unsigned short* X3  = (unsigned short*)attn;
  unsigned short* Wt3 = X3 + (size_t)3 * MT * DD;

  dim3 gc(MT * DD / (256 * 8), 3);                   // 2048 x 3
  conv_x3<<<gc, 256, 0, stream>>>(query, key, value, X3);

  dim3 gw(DD / 64, DD / 64, 3);                      // 16 x 16 x 3
  conv_wT3<<<gw, 256, 0, stream>>>(Wq, Wk, Wv, Wt3);

  dim3 gg(MT / 128, DD / 128, 3);                    // 32 x 8 x 3 = 768 blocks
  gemm3<<<gg, 256, 0, stream>>>(X3, Wt3, bq, bk, bv, Qb, Kb, Vt);

  dim3 g2(2048);                                     // 1D, XCD-swizzled
  fused_attn<<<g2, 256, 0, stream>>>(Qb, Kb, Vt, attn, ctx);
}